// Round 1
// baseline (85.182 us; speedup 1.0000x reference)
//
#include <hip/hip_runtime.h>
#include <hip/hip_bf16.h>

// ============================================================================
// AdaptiveDiffusionConv: out[b,n,o,t] = relu( sum_{k,f} Theta[k,f,o] * rhs_k )
//   rhs0 = x, rhs1 = a^T x, rhs2 = a^T rhs1   (a = adj .* spatial_attention)
// Key identity: (a@a)^T x = a^T (a^T x)  -> two [1024x1024]^T @ [1024x192]
// batched GEMMs instead of an N^3 matrix power.
//
// Layouts (all bf16 in workspace):
//   aT[b][n][m]  = a[b][m][n]          (B-operand, k=m contiguous)
//   xT[b][j][m]  = x[b][m][f][t], j=f*12+t   (A-operand, k=m contiguous)
//   rhs1T/rhs2T[b][j][n]               (GEMM out, row-major; feeds next GEMM)
// ============================================================================

typedef __attribute__((ext_vector_type(8))) __bf16 bf16x8;
typedef __attribute__((ext_vector_type(4))) float  f32x4;
typedef __attribute__((ext_vector_type(8))) short  short8;

__device__ inline unsigned short f32_to_bf16(float f) {
    unsigned int u = __builtin_bit_cast(unsigned int, f);
    unsigned int r = u + 0x7FFFu + ((u >> 16) & 1u);   // RNE
    return (unsigned short)(r >> 16);
}
__device__ inline float bf16_to_f32(unsigned short u) {
    unsigned int x = ((unsigned int)u) << 16;
    return __builtin_bit_cast(float, x);
}

// ---------------------------------------------------------------------------
// prep_a: aT[b][n][m] = bf16(adj[m][n] * sa[b][m][n]); 32x32 LDS tile transpose
// grid (32 n-tiles, 32 m-tiles, 16 b), block 256
// ---------------------------------------------------------------------------
__global__ void prep_a(const float* __restrict__ sa, const float* __restrict__ adj,
                       unsigned short* __restrict__ aT)
{
    __shared__ float tile[32][33];
    const int b  = blockIdx.z;
    const int m0 = blockIdx.y * 32;
    const int n0 = blockIdx.x * 32;
    const int tid = threadIdx.x;
    const int c  = tid & 31;
    const int r4 = tid >> 5;          // 0..7
    const float* sab = sa + (size_t)b * 1024 * 1024;
#pragma unroll
    for (int i = 0; i < 4; i++) {
        int rr = r4 + i * 8;
        size_t idx = (size_t)(m0 + rr) * 1024 + (n0 + c);
        tile[rr][c] = adj[idx] * sab[idx];
    }
    __syncthreads();
    unsigned short* aTb = aT + (size_t)b * 1024 * 1024;
#pragma unroll
    for (int i = 0; i < 4; i++) {
        int rr = r4 + i * 8;          // n offset in output
        aTb[(size_t)(n0 + rr) * 1024 + (m0 + c)] = f32_to_bf16(tile[c][rr]);
    }
}

// ---------------------------------------------------------------------------
// prep_x: xT[b][j][m] = bf16(x[b][m][j]), j = f*12+t (192)
// grid (32 m-tiles, 6 j-tiles, 16 b), block 256
// ---------------------------------------------------------------------------
__global__ void prep_x(const float* __restrict__ x, unsigned short* __restrict__ xT)
{
    __shared__ float tile[32][33];
    const int b  = blockIdx.z;
    const int j0 = blockIdx.y * 32;
    const int m0 = blockIdx.x * 32;
    const int tid = threadIdx.x;
    const int c  = tid & 31;
    const int r4 = tid >> 5;
    const float* xb = x + (size_t)b * 1024 * 192;
#pragma unroll
    for (int i = 0; i < 4; i++) {
        int rr = r4 + i * 8;          // m
        tile[rr][c] = xb[(size_t)(m0 + rr) * 192 + (j0 + c)];
    }
    __syncthreads();
    unsigned short* xTb = xT + (size_t)b * 192 * 1024;
#pragma unroll
    for (int i = 0; i < 4; i++) {
        int rr = r4 + i * 8;          // j
        xTb[(size_t)(j0 + rr) * 1024 + (m0 + c)] = f32_to_bf16(tile[c][rr]);
    }
}

// ---------------------------------------------------------------------------
// gemm_tn: Cout[b][j][n] (bf16) = sum_m Aop[b][j][m] * Bop[b][n][m]
//   Aop: [B][192][1024]  (rows j, k contiguous)
//   Bop: [B][1024][1024] (aT; B-operand col n, k contiguous)
// block tile 96j x 128n, BK=64, 4 waves (2x2), wave tile 48x64,
// 12x mfma_f32_16x16x32_bf16 accumulators per wave.
// grid (8 n-tiles, 2 j-tiles, 16 b), block 256
// ---------------------------------------------------------------------------
#define GEMM_BJ 96
#define GEMM_BN 128
#define GEMM_BK 64
#define LDS_STRIDE 72   // 64 + 8 pad -> 144B row = 9 x 16B (conflict-friendly)

__global__ __launch_bounds__(256, 2)
void gemm_tn(const unsigned short* __restrict__ Aop,
             const unsigned short* __restrict__ Bop,
             unsigned short* __restrict__ Cout)
{
    const int b  = blockIdx.z;
    const int j0 = blockIdx.y * GEMM_BJ;
    const int n0 = blockIdx.x * GEMM_BN;
    const unsigned short* Ab = Aop + (size_t)b * 192 * 1024;
    const unsigned short* Bb = Bop + (size_t)b * 1024 * 1024;

    __shared__ unsigned short Alds[GEMM_BJ][LDS_STRIDE];
    __shared__ unsigned short Blds[GEMM_BN][LDS_STRIDE];

    const int tid  = threadIdx.x;
    const int lane = tid & 63;
    const int wave = tid >> 6;      // 0..3
    const int wj   = wave >> 1;     // 0..1
    const int wn   = wave & 1;      // 0..1
    const int lr   = lane & 15;     // row/col offset within 16
    const int lk   = (lane >> 4) * 8;

    f32x4 acc[3][4];
#pragma unroll
    for (int i = 0; i < 3; i++)
#pragma unroll
        for (int j = 0; j < 4; j++) acc[i][j] = f32x4{0.f, 0.f, 0.f, 0.f};

    for (int m0 = 0; m0 < 1024; m0 += GEMM_BK) {
        // ---- stage: global -> regs (A: 96x64 = 768 chunks/8, B: 128x64 = 1024)
        short8 aval[3], bval[4];
#pragma unroll
        for (int i = 0; i < 3; i++) {
            int id = tid + i * 256, r = id >> 3, c = id & 7;
            aval[i] = *reinterpret_cast<const short8*>(Ab + (size_t)(j0 + r) * 1024 + m0 + c * 8);
        }
#pragma unroll
        for (int i = 0; i < 4; i++) {
            int id = tid + i * 256, r = id >> 3, c = id & 7;
            bval[i] = *reinterpret_cast<const short8*>(Bb + (size_t)(n0 + r) * 1024 + m0 + c * 8);
        }
        __syncthreads();            // previous iter's LDS reads done
#pragma unroll
        for (int i = 0; i < 3; i++) {
            int id = tid + i * 256, r = id >> 3, c = id & 7;
            *reinterpret_cast<short8*>(&Alds[r][c * 8]) = aval[i];
        }
#pragma unroll
        for (int i = 0; i < 4; i++) {
            int id = tid + i * 256, r = id >> 3, c = id & 7;
            *reinterpret_cast<short8*>(&Blds[r][c * 8]) = bval[i];
        }
        __syncthreads();
        // ---- compute: two k=32 sub-steps
#pragma unroll
        for (int kk = 0; kk < GEMM_BK; kk += 32) {
            bf16x8 af[3], bfr[4];
#pragma unroll
            for (int ri = 0; ri < 3; ri++)
                af[ri] = __builtin_bit_cast(bf16x8,
                    *reinterpret_cast<const short8*>(&Alds[wj * 48 + ri * 16 + lr][kk + lk]));
#pragma unroll
            for (int ci = 0; ci < 4; ci++)
                bfr[ci] = __builtin_bit_cast(bf16x8,
                    *reinterpret_cast<const short8*>(&Blds[wn * 64 + ci * 16 + lr][kk + lk]));
#pragma unroll
            for (int ri = 0; ri < 3; ri++)
#pragma unroll
                for (int ci = 0; ci < 4; ci++)
                    acc[ri][ci] = __builtin_amdgcn_mfma_f32_16x16x32_bf16(
                        af[ri], bfr[ci], acc[ri][ci], 0, 0, 0);
        }
    }
    // ---- epilogue: D layout col = lane&15, row = (lane>>4)*4 + reg
    unsigned short* Cb = Cout + (size_t)b * 192 * 1024;
    const int jw = j0 + wj * 48;
    const int nw = n0 + wn * 64;
#pragma unroll
    for (int ri = 0; ri < 3; ri++)
#pragma unroll
        for (int ci = 0; ci < 4; ci++) {
            int col = nw + ci * 16 + lr;
#pragma unroll
            for (int r = 0; r < 4; r++) {
                int row = jw + ri * 16 + (lane >> 4) * 4 + r;
                Cb[(size_t)row * 1024 + col] = f32_to_bf16(acc[ri][ci][r]);
            }
        }
}

// ---------------------------------------------------------------------------
// final_contract: out[b,n,o,t] = relu( sum_f Th0[f,o]*xT + Th1[f,o]*r1 + Th2[f,o]*r2 )
// thread = (b, n, t-quad); grid 192 blocks x 256
// ---------------------------------------------------------------------------
__global__ __launch_bounds__(256)
void final_contract(const unsigned short* __restrict__ xT,
                    const unsigned short* __restrict__ r1,
                    const unsigned short* __restrict__ r2,
                    const float* __restrict__ Theta,   // [3][16][16]
                    float* __restrict__ out)           // [B][1024][16][12]
{
    __shared__ float th[3][16][16];
    const int tid = threadIdx.x;
    for (int i = tid; i < 768; i += 256) ((float*)th)[i] = Theta[i];
    __syncthreads();

    const int gid = blockIdx.x * 256 + tid;   // 49152 = 16b * 1024n * 3tq
    const int n   = gid & 1023;
    const int btq = gid >> 10;                // 0..47
    const int tq  = btq % 3;                  // t-quad
    const int b   = btq / 3;
    const size_t base = (size_t)b * 192 * 1024 + n;

    float acc[4][16];
#pragma unroll
    for (int tt = 0; tt < 4; tt++)
#pragma unroll
        for (int o = 0; o < 16; o++) acc[tt][o] = 0.f;

#pragma unroll
    for (int f = 0; f < 16; f++) {
        size_t off = base + (size_t)(f * 12 + tq * 4) * 1024;
        float v0[4], v1[4], v2[4];
#pragma unroll
        for (int tt = 0; tt < 4; tt++) {
            v0[tt] = bf16_to_f32(xT[off + (size_t)tt * 1024]);
            v1[tt] = bf16_to_f32(r1[off + (size_t)tt * 1024]);
            v2[tt] = bf16_to_f32(r2[off + (size_t)tt * 1024]);
        }
        const f32x4* t0 = reinterpret_cast<const f32x4*>(&th[0][f][0]);
        const f32x4* t1 = reinterpret_cast<const f32x4*>(&th[1][f][0]);
        const f32x4* t2 = reinterpret_cast<const f32x4*>(&th[2][f][0]);
#pragma unroll
        for (int q = 0; q < 4; q++) {
            f32x4 w0 = t0[q], w1 = t1[q], w2 = t2[q];
#pragma unroll
            for (int tt = 0; tt < 4; tt++)
#pragma unroll
                for (int e = 0; e < 4; e++)
                    acc[tt][q * 4 + e] += v0[tt] * w0[e] + v1[tt] * w1[e] + v2[tt] * w2[e];
        }
    }
    // stores: out[..][o][tq*4 .. +4) -> 16B-aligned float4
    float* outp = out + ((size_t)(b * 1024 + n) * 16) * 12 + tq * 4;
#pragma unroll
    for (int o = 0; o < 16; o++) {
        f32x4 v;
#pragma unroll
        for (int tt = 0; tt < 4; tt++) v[tt] = fmaxf(acc[tt][o], 0.f);
        *reinterpret_cast<f32x4*>(&outp[o * 12]) = v;
    }
}

// ---------------------------------------------------------------------------
extern "C" void kernel_launch(void* const* d_in, const int* in_sizes, int n_in,
                              void* d_out, int out_size, void* d_ws, size_t ws_size,
                              hipStream_t stream)
{
    const float* x     = (const float*)d_in[0];   // [16][1024][16][12]
    const float* sa    = (const float*)d_in[1];   // [16][1024][1024]
    const float* adj   = (const float*)d_in[2];   // [1024][1024]
    const float* Theta = (const float*)d_in[3];   // [3][16][16]
    float* out = (float*)d_out;

    char* ws = (char*)d_ws;
    const size_t SZ_AT = (size_t)16 * 1024 * 1024 * 2;  // 32 MB
    const size_t SZ_XT = (size_t)16 * 192  * 1024 * 2;  //  6 MB
    unsigned short* aT = (unsigned short*)ws;
    unsigned short* xT = (unsigned short*)(ws + SZ_AT);
    unsigned short* r1 = (unsigned short*)(ws + SZ_AT + SZ_XT);
    unsigned short* r2 = (unsigned short*)(ws + SZ_AT + 2 * SZ_XT);

    prep_a<<<dim3(32, 32, 16), 256, 0, stream>>>(sa, adj, aT);
    prep_x<<<dim3(32, 6, 16), 256, 0, stream>>>(x, xT);
    gemm_tn<<<dim3(8, 2, 16), 256, 0, stream>>>(xT, aT, r1);   // rhs1T = x^T-chain
    gemm_tn<<<dim3(8, 2, 16), 256, 0, stream>>>(r1, aT, r2);   // rhs2T
    final_contract<<<dim3(192), 256, 0, stream>>>(xT, r1, r2, Theta, out);
}